// Round 10
// baseline (48.150 us; speedup 1.0000x reference)
//
#include <hip/hip_runtime.h>
#include <math.h>

#define NROWS 128
#define KDIM  1024
#define ODIM  512
#define NB    32
#define BS    32

__device__ __forceinline__ int clz32(unsigned x) { return x ? __builtin_clz(x) : 32; }

// FROZEN (r7/r8/r9-verified): kept = P - ((t&m)-(h&m)) via v_bfe_u32.
// DO NOT rewrite into high-mask forms ((t&~m)-(h&~m) / shift-align) —
// empirically wrong on HW (r3/r4/r6, absmax 1.375).
__device__ __forceinline__ int naf_keep(int P, int isum) {
  const int h = P >> 1;
  const int t = P + h;
  const int lz = __builtin_clz(((unsigned)(t ^ h)) | 1u);
  int drop = isum - lz;
  drop = drop < 0 ? 0 : (drop > 31 ? 31 : drop);   // v_med3_i32
  return P - ((int)__builtin_amdgcn_ubfe(t, 0, drop)
            - (int)__builtin_amdgcn_ubfe(h, 0, drop));
}

// ---------------- prep1: 320 blocks x 64 threads. blocks 0..63 quantize x rows,
// blocks 64..319 quantize w rows. Per-task math identical to r9.
__global__ void prep_kernel(const float* __restrict__ x, const float* __restrict__ wgt,
                            unsigned short* __restrict__ xp, unsigned char* __restrict__ wq,
                            float* __restrict__ xs, float* __restrict__ lxs,
                            float* __restrict__ wsc, float* __restrict__ lws) {
  const int bid = blockIdx.x;
  if (bid < 64) {
    int tid = bid * 64 + threadIdx.x;             // 0..4095 = 128 rows x 32 blocks
    int row = tid >> 5, blk = tid & 31;
    const float4* p = (const float4*)(x + (size_t)row * KDIM + blk * BS);
    float v[32];
    float m = 0.f;
#pragma unroll
    for (int i = 0; i < 8; ++i) {
      float4 f = p[i];
      v[4*i+0] = f.x; v[4*i+1] = f.y; v[4*i+2] = f.z; v[4*i+3] = f.w;
      m = fmaxf(m, fmaxf(fmaxf(fabsf(f.x), fabsf(f.y)), fmaxf(fabsf(f.z), fabsf(f.w))));
    }
    float scale = fmaxf(m / 1.984375f, 1e-30f);
    int q[32], e[32], emax = -60;
#pragma unroll
    for (int i = 0; i < 32; ++i) {
      float t = v[i] / scale * 64.0f;     // IEEE div + exact pow2 mul, matches ref
      int qi = (int)rintf(t);             // round-half-even, matches jnp.round
      q[i] = qi;
      int a = qi < 0 ? -qi : qi;
      int ei = a ? (31 - clz32((unsigned)a)) - 6 : -60;
      e[i] = ei;
      emax = ei > emax ? ei : emax;
    }
    unsigned short u[32];
#pragma unroll
    for (int i = 0; i < 32; ++i)
      u[i] = (unsigned short)(((emax - e[i]) << 8) | (q[i] & 0xFF));
    uint4* dst = (uint4*)(xp + (size_t)row * KDIM + blk * BS);
#pragma unroll
    for (int i = 0; i < 4; ++i) {
      uint4 w4;
      w4.x = (unsigned)u[8*i+0] | ((unsigned)u[8*i+1] << 16);
      w4.y = (unsigned)u[8*i+2] | ((unsigned)u[8*i+3] << 16);
      w4.z = (unsigned)u[8*i+4] | ((unsigned)u[8*i+5] << 16);
      w4.w = (unsigned)u[8*i+6] | ((unsigned)u[8*i+7] << 16);
      dst[i] = w4;
    }
    xs[tid] = scale;
    lxs[tid] = (float)log2((double)scale);
  } else {
    int tid = (bid - 64) * 64 + threadIdx.x;      // 0..16383 = 512 rows x 32 blocks
    int row = tid >> 5, blk = tid & 31;
    const float4* p = (const float4*)(wgt + (size_t)row * KDIM + blk * BS);
    float v[32];
    float m = 0.f;
#pragma unroll
    for (int i = 0; i < 8; ++i) {
      float4 f = p[i];
      v[4*i+0] = f.x; v[4*i+1] = f.y; v[4*i+2] = f.z; v[4*i+3] = f.w;
      m = fmaxf(m, fmaxf(fmaxf(fabsf(f.x), fabsf(f.y)), fmaxf(fabsf(f.z), fabsf(f.w))));
    }
    float scale = fmaxf(m / 1.984375f, 1e-30f);
    unsigned char c[32];
#pragma unroll
    for (int i = 0; i < 32; ++i) {
      float t = v[i] / scale * 64.0f;
      int qi = (int)rintf(t);
      c[i] = (unsigned char)(qi & 0xFF);
    }
    uint4* dst = (uint4*)(wq + (size_t)row * KDIM + blk * BS);
#pragma unroll
    for (int i = 0; i < 2; ++i) {
      uint4 w4;
      w4.x = (unsigned)c[16*i+ 0] | ((unsigned)c[16*i+ 1] << 8) | ((unsigned)c[16*i+ 2] << 16) | ((unsigned)c[16*i+ 3] << 24);
      w4.y = (unsigned)c[16*i+ 4] | ((unsigned)c[16*i+ 5] << 8) | ((unsigned)c[16*i+ 6] << 16) | ((unsigned)c[16*i+ 7] << 24);
      w4.z = (unsigned)c[16*i+ 8] | ((unsigned)c[16*i+ 9] << 8) | ((unsigned)c[16*i+10] << 16) | ((unsigned)c[16*i+11] << 24);
      w4.w = (unsigned)c[16*i+12] | ((unsigned)c[16*i+13] << 8) | ((unsigned)c[16*i+14] << 16) | ((unsigned)c[16*i+15] << 24);
      dst[i] = w4;
    }
    wsc[tid] = scale;
    lws[tid] = (float)log2((double)scale);
  }
}

// ---------------- prep2: s-table. s(n,o,b) = sbase(n,o) - ice(n,o,b),
// sbase = 24 + min(iemax,0), iemax = (int)max_b floorf(lx+lw).
// Same float ops in same order as r9's in-main computation -> bit-identical.
__global__ void prep_s_kernel(const float* __restrict__ lxs,
                              const float* __restrict__ lws,
                              short* __restrict__ sTab) {
  const int t = blockIdx.x * blockDim.x + threadIdx.x;   // 0..65535
  const int n = t >> 9, o = t & 511;
  const float* lx = lxs + n * NB;
  const float* lw = lws + o * NB;
  float fl[32];
  float emf = -1e30f;
#pragma unroll
  for (int b = 0; b < NB; ++b) {
    float f = floorf(lx[b] + lw[b]);
    fl[b] = f;
    emf = fmaxf(emf, f);
  }
  const int iemax = (int)emf;
  const int sbase = 24 + (iemax < 0 ? iemax : 0);
  uint4 pk[4];
#pragma unroll
  for (int g = 0; g < 4; ++g) {
    unsigned wrds[4];
#pragma unroll
    for (int k = 0; k < 4; ++k) {
      int b = g * 8 + k * 2;
      int s0 = sbase - (int)fl[b];
      int s1 = sbase - (int)fl[b + 1];
      wrds[k] = ((unsigned)s0 & 0xFFFFu) | ((unsigned)s1 << 16);
    }
    pk[g].x = wrds[0]; pk[g].y = wrds[1]; pk[g].z = wrds[2]; pk[g].w = wrds[3];
  }
  uint4* dst = (uint4*)(sTab + (size_t)t * NB);
#pragma unroll
  for (int g = 0; g < 4; ++g) dst[g] = pk[g];
}

// ---------------- main: 8n x 16o tile, 8-way K-split, 1024 threads, 2 blocks/CU
__global__ __launch_bounds__(1024, 8)
void msd_main_kernel(const unsigned short* __restrict__ xp,
                     const unsigned char* __restrict__ wq,
                     const float* __restrict__ xs,
                     const float* __restrict__ wsc,
                     const short* __restrict__ sTab,
                     const float* __restrict__ bias, float* __restrict__ out) {
  __shared__ unsigned short sx[8][1032];    // row stride 2064B -> banks 4*tn apart
  __shared__ unsigned char  swq[16][1040];  // 2-way conflict only (free)
  __shared__ float sxs[8][33], sws[16][33];
  __shared__ float sred[7 * 128];
  const int tid = threadIdx.x;
  const int n0 = blockIdx.x * 8, o0 = blockIdx.y * 16;

  // stage x tile: 8 rows x 1024 packed ushorts (1 uint4 per thread)
  {
    int r = tid >> 7, c = tid & 127;
    uint4 d = ((const uint4*)(xp + (size_t)(n0 + r) * KDIM))[c];
    *(uint4*)&sx[r][c * 8] = d;
  }
  // stage w tile: 16 rows x 1024 bytes (1 uint4 per thread)
  {
    int r = tid >> 6, c = tid & 63;
    uint4 d = ((const uint4*)(wq + (size_t)(o0 + r) * KDIM))[c];
    *(uint4*)&swq[r][c * 16] = d;
  }
  {
    int r = tid >> 5, b = tid & 31;
    if (tid < 256) sxs[r][b] = xs[(n0 + r) * NB + b];
    if (tid < 512) sws[r][b] = wsc[(o0 + r) * NB + b];
  }
  __syncthreads();

  const int kh = tid >> 7, idx = tid & 127, tn = idx >> 4, to = idx & 15;
  const int b0 = kh * 4;

  // per-thread s values for its 4 MX blocks (precomputed, bit-identical)
  const short4 sv = *(const short4*)(sTab
      + ((size_t)(n0 + tn) * ODIM + (o0 + to)) * NB + b0);
  const int s_arr0 = (int)sv.x, s_arr1 = (int)sv.y,
            s_arr2 = (int)sv.z, s_arr3 = (int)sv.w;

  float facc = 0.f;
#pragma unroll
  for (int bb = 0; bb < 4; ++bb) {
    const int b = b0 + bb;
    const int s = bb == 0 ? s_arr0 : (bb == 1 ? s_arr1 : (bb == 2 ? s_arr2 : s_arr3));
    uint4 xv0 = *(const uint4*)&sx[tn][b * 32 + 0];
    uint4 xv1 = *(const uint4*)&sx[tn][b * 32 + 8];
    uint4 xv2 = *(const uint4*)&sx[tn][b * 32 + 16];
    uint4 xv3 = *(const uint4*)&sx[tn][b * 32 + 24];
    unsigned xd[16] = {xv0.x, xv0.y, xv0.z, xv0.w, xv1.x, xv1.y, xv1.z, xv1.w,
                       xv2.x, xv2.y, xv2.z, xv2.w, xv3.x, xv3.y, xv3.z, xv3.w};
    uint4 wv0 = *(const uint4*)&swq[to][b * 32];
    uint4 wv1 = *(const uint4*)&swq[to][b * 32 + 16];
    unsigned wb[8] = {wv0.x, wv0.y, wv0.z, wv0.w, wv1.x, wv1.y, wv1.z, wv1.w};
    int bacc = 0;
#pragma unroll
    for (int j = 0; j < 16; ++j) {        // 2 elements per x-dword
      const unsigned xw = xd[j];
      const unsigned ww = wb[j >> 1];
      const int ix0 = __builtin_amdgcn_sbfe((int)xw, 0, 8);      // v_bfe_i32
      const int in0 = (int)__builtin_amdgcn_ubfe(xw, 8, 8);      // v_bfe_u32
      const int ix1 = __builtin_amdgcn_sbfe((int)xw, 16, 8);
      const int in1 = (int)(xw >> 24);
      int iw0, iw1;
      if (j & 1) { iw0 = __builtin_amdgcn_sbfe((int)ww, 16, 8);
                   iw1 = __builtin_amdgcn_sbfe((int)ww, 24, 8); }
      else       { iw0 = __builtin_amdgcn_sbfe((int)ww, 0, 8);
                   iw1 = __builtin_amdgcn_sbfe((int)ww, 8, 8); }
      bacc += naf_keep(__mul24(ix0, iw0), in0 + s);     // |ix|,|iw| <= 127: exact
      bacc += naf_keep(__mul24(ix1, iw1), in1 + s);
    }
    facc += sxs[tn][b] * sws[to][b] * (float)bacc;  // exact: block_dot = bacc/4096
  }

  if (kh) sred[(kh - 1) * 128 + idx] = facc;
  __syncthreads();
  if (!kh) {
    float r = facc;
#pragma unroll
    for (int p = 0; p < 7; ++p) r += sred[p * 128 + idx];
    r = r * (1.0f / 4096.0f) + bias[o0 + to];
    out[(size_t)(n0 + tn) * ODIM + (o0 + to)] = r;
  }
}

extern "C" void kernel_launch(void* const* d_in, const int* in_sizes, int n_in,
                              void* d_out, int out_size, void* d_ws, size_t ws_size,
                              hipStream_t stream) {
  const float* x    = (const float*)d_in[0];
  const float* wgt  = (const float*)d_in[1];
  const float* bias = (const float*)d_in[2];
  float* out = (float*)d_out;
  char* ws = (char*)d_ws;
  // workspace layout (16B-aligned)
  unsigned short* xp  = (unsigned short*)(ws + 0);       // 262144 B
  unsigned char*  wq  = (unsigned char*)(ws + 262144);   // 524288 B
  float* xs   = (float*)(ws + 786432);                   // 16384 B
  float* lxs  = (float*)(ws + 802816);                   // 16384 B
  float* wsc  = (float*)(ws + 819200);                   // 65536 B
  float* lws  = (float*)(ws + 884736);                   // 65536 B
  short* sTab = (short*)(ws + 950272);                   // 128*512*32*2 = 4 MiB

  hipLaunchKernelGGL(prep_kernel, dim3(320), dim3(64), 0, stream,
                     x, wgt, xp, wq, xs, lxs, wsc, lws);
  hipLaunchKernelGGL(prep_s_kernel, dim3(256), dim3(256), 0, stream,
                     lxs, lws, sTab);
  hipLaunchKernelGGL(msd_main_kernel, dim3(16, 32), dim3(1024), 0, stream,
                     xp, wq, xs, wsc, sTab, bias, out);
}

// Round 11
// 37.315 us; speedup vs baseline: 1.2904x; 1.2904x over previous
//
#include <hip/hip_runtime.h>
#include <math.h>

#define NROWS 128
#define KDIM  1024
#define ODIM  512
#define NB    32
#define BS    32

__device__ __forceinline__ int clz32(unsigned x) { return x ? __builtin_clz(x) : 32; }

// FROZEN SEMANTICS (r7/r8/r9-verified): kept = P - ((t&m)-(h&m)), m = 2^drop-1,
// h=P>>1 (arith), t=P+h, drop = clamp(isum - clz((t^h)|1), 0, 31).
// This round the core is INLINE ASM (11 insts, one per op) — pins the emitted
// stream, and no optimizer pass can re-fold it into the broken high-mask form
// (r3/r4/r6, absmax 1.375).
__device__ __forceinline__ int naf_keep(int P, int isum) {
  int kept, h, t, c, dr;
  asm volatile(
      "v_ashrrev_i32 %1, 1, %5\n\t"    // h  = P >> 1 (arith)
      "v_add_u32     %2, %5, %1\n\t"   // t  = P + h
      "v_xor_b32     %3, %2, %1\n\t"   // c  = t ^ h
      "v_or_b32      %3, 1, %3\n\t"    // c |= 1
      "v_ffbh_u32    %3, %3\n\t"       // c  = clz(c)
      "v_sub_u32     %4, %6, %3\n\t"   // dr = isum - c
      "v_med3_i32    %4, %4, 0, 31\n\t"// dr = clamp(dr, 0, 31)
      "v_bfe_u32     %3, %2, 0, %4\n\t"// c  = t & m
      "v_bfe_u32     %2, %1, 0, %4\n\t"// t' = h & m
      "v_sub_u32     %3, %3, %2\n\t"   // dropped = (t&m)-(h&m)
      "v_sub_u32     %0, %5, %3\n\t"   // kept = P - dropped
      : "=v"(kept), "=&v"(h), "=&v"(t), "=&v"(c), "=&v"(dr)
      : "v"(P), "v"(isum));
  return kept;
}

// ---------------- merged prep (r9-identical): blocks 0..15 x, 16..79 w
__global__ void prep_kernel(const float* __restrict__ x, const float* __restrict__ wgt,
                            unsigned short* __restrict__ xp, unsigned char* __restrict__ wq,
                            float* __restrict__ xs, float* __restrict__ lxs,
                            float* __restrict__ wsc, float* __restrict__ lws) {
  const int bid = blockIdx.x;
  if (bid < 16) {
    int tid = bid * 256 + threadIdx.x;            // 0..4095 = 128 rows x 32 blocks
    int row = tid >> 5, blk = tid & 31;
    const float4* p = (const float4*)(x + (size_t)row * KDIM + blk * BS);
    float v[32];
    float m = 0.f;
#pragma unroll
    for (int i = 0; i < 8; ++i) {
      float4 f = p[i];
      v[4*i+0] = f.x; v[4*i+1] = f.y; v[4*i+2] = f.z; v[4*i+3] = f.w;
      m = fmaxf(m, fmaxf(fmaxf(fabsf(f.x), fabsf(f.y)), fmaxf(fabsf(f.z), fabsf(f.w))));
    }
    float scale = fmaxf(m / 1.984375f, 1e-30f);
    int q[32], e[32], emax = -60;
#pragma unroll
    for (int i = 0; i < 32; ++i) {
      float t = v[i] / scale * 64.0f;     // IEEE div + exact pow2 mul, matches ref
      int qi = (int)rintf(t);             // round-half-even, matches jnp.round
      q[i] = qi;
      int a = qi < 0 ? -qi : qi;
      int ei = a ? (31 - clz32((unsigned)a)) - 6 : -60;
      e[i] = ei;
      emax = ei > emax ? ei : emax;
    }
    unsigned short u[32];
#pragma unroll
    for (int i = 0; i < 32; ++i)
      u[i] = (unsigned short)(((emax - e[i]) << 8) | (q[i] & 0xFF));
    uint4* dst = (uint4*)(xp + (size_t)row * KDIM + blk * BS);
#pragma unroll
    for (int i = 0; i < 4; ++i) {
      uint4 w4;
      w4.x = (unsigned)u[8*i+0] | ((unsigned)u[8*i+1] << 16);
      w4.y = (unsigned)u[8*i+2] | ((unsigned)u[8*i+3] << 16);
      w4.z = (unsigned)u[8*i+4] | ((unsigned)u[8*i+5] << 16);
      w4.w = (unsigned)u[8*i+6] | ((unsigned)u[8*i+7] << 16);
      dst[i] = w4;
    }
    xs[tid] = scale;
    lxs[tid] = (float)log2((double)scale);
  } else {
    int tid = (bid - 16) * 256 + threadIdx.x;     // 0..16383 = 512 rows x 32 blocks
    int row = tid >> 5, blk = tid & 31;
    const float4* p = (const float4*)(wgt + (size_t)row * KDIM + blk * BS);
    float v[32];
    float m = 0.f;
#pragma unroll
    for (int i = 0; i < 8; ++i) {
      float4 f = p[i];
      v[4*i+0] = f.x; v[4*i+1] = f.y; v[4*i+2] = f.z; v[4*i+3] = f.w;
      m = fmaxf(m, fmaxf(fmaxf(fabsf(f.x), fabsf(f.y)), fmaxf(fabsf(f.z), fabsf(f.w))));
    }
    float scale = fmaxf(m / 1.984375f, 1e-30f);
    unsigned char c[32];
#pragma unroll
    for (int i = 0; i < 32; ++i) {
      float t = v[i] / scale * 64.0f;
      int qi = (int)rintf(t);
      c[i] = (unsigned char)(qi & 0xFF);
    }
    uint4* dst = (uint4*)(wq + (size_t)row * KDIM + blk * BS);
#pragma unroll
    for (int i = 0; i < 2; ++i) {
      uint4 w4;
      w4.x = (unsigned)c[16*i+ 0] | ((unsigned)c[16*i+ 1] << 8) | ((unsigned)c[16*i+ 2] << 16) | ((unsigned)c[16*i+ 3] << 24);
      w4.y = (unsigned)c[16*i+ 4] | ((unsigned)c[16*i+ 5] << 8) | ((unsigned)c[16*i+ 6] << 16) | ((unsigned)c[16*i+ 7] << 24);
      w4.z = (unsigned)c[16*i+ 8] | ((unsigned)c[16*i+ 9] << 8) | ((unsigned)c[16*i+10] << 16) | ((unsigned)c[16*i+11] << 24);
      w4.w = (unsigned)c[16*i+12] | ((unsigned)c[16*i+13] << 8) | ((unsigned)c[16*i+14] << 16) | ((unsigned)c[16*i+15] << 24);
      dst[i] = w4;
    }
    wsc[tid] = scale;
    lws[tid] = (float)log2((double)scale);
  }
}

// ---------------- main (r9-identical structure): 8n x 16o tile, 8-way K-split,
// 1024 threads, 2 blocks/CU
__global__ __launch_bounds__(1024, 8)
void msd_main_kernel(const unsigned short* __restrict__ xp,
                     const unsigned char* __restrict__ wq,
                     const float* __restrict__ xs, const float* __restrict__ lxs,
                     const float* __restrict__ wsc, const float* __restrict__ lws,
                     const float* __restrict__ bias, float* __restrict__ out) {
  __shared__ unsigned short sx[8][1032];    // row stride 2064B -> banks 4*tn apart
  __shared__ unsigned char  swq[16][1040];  // 2-way conflict only (free)
  __shared__ float sxs[8][33], slx[8][33], sws[16][33], slw[16][33];
  __shared__ float sred[7 * 128];
  const int tid = threadIdx.x;
  const int n0 = blockIdx.x * 8, o0 = blockIdx.y * 16;

  // stage x tile: 8 rows x 1024 packed ushorts (1 uint4 per thread)
  {
    int r = tid >> 7, c = tid & 127;
    uint4 d = ((const uint4*)(xp + (size_t)(n0 + r) * KDIM))[c];
    *(uint4*)&sx[r][c * 8] = d;
  }
  // stage w tile: 16 rows x 1024 bytes (1 uint4 per thread)
  {
    int r = tid >> 6, c = tid & 63;
    uint4 d = ((const uint4*)(wq + (size_t)(o0 + r) * KDIM))[c];
    *(uint4*)&swq[r][c * 16] = d;
  }
  {
    int r = tid >> 5, b = tid & 31;
    if (tid < 256) {
      sxs[r][b] = xs[(n0 + r) * NB + b];
      slx[r][b] = lxs[(n0 + r) * NB + b];
    }
    if (tid < 512) {
      sws[r][b] = wsc[(o0 + r) * NB + b];
      slw[r][b] = lws[(o0 + r) * NB + b];
    }
  }
  __syncthreads();

  const int kh = tid >> 7, idx = tid & 127, tn = idx >> 4, to = idx & 15;

  // e_max over blocks (combined_e = floor(lx + lw)) — proven scalar path
  float emf = -1e30f;
#pragma unroll
  for (int b = 0; b < NB; ++b)
    emf = fmaxf(emf, floorf(slx[tn][b] + slw[to][b]));
  const int iemax = (int)emf;
  // s = 32 - dbase = 24 + min(iemax,0) - ice   (dbase = 8+max(emax,0)-emax+ice)
  const int sbase = 24 + (iemax < 0 ? iemax : 0);

  float facc = 0.f;
  const int b0 = kh * 4;
#pragma unroll 1
  for (int bb = 0; bb < 4; ++bb) {
    const int b = b0 + bb;
    const int ice = (int)floorf(slx[tn][b] + slw[to][b]);
    const int s = sbase - ice;
    uint4 xv0 = *(const uint4*)&sx[tn][b * 32 + 0];
    uint4 xv1 = *(const uint4*)&sx[tn][b * 32 + 8];
    uint4 xv2 = *(const uint4*)&sx[tn][b * 32 + 16];
    uint4 xv3 = *(const uint4*)&sx[tn][b * 32 + 24];
    unsigned xd[16] = {xv0.x, xv0.y, xv0.z, xv0.w, xv1.x, xv1.y, xv1.z, xv1.w,
                       xv2.x, xv2.y, xv2.z, xv2.w, xv3.x, xv3.y, xv3.z, xv3.w};
    uint4 wv0 = *(const uint4*)&swq[to][b * 32];
    uint4 wv1 = *(const uint4*)&swq[to][b * 32 + 16];
    unsigned wb[8] = {wv0.x, wv0.y, wv0.z, wv0.w, wv1.x, wv1.y, wv1.z, wv1.w};
    int bacc = 0;
#pragma unroll
    for (int j = 0; j < 16; ++j) {        // 2 elements per x-dword
      const unsigned xw = xd[j];
      const unsigned ww = wb[j >> 1];
      const int ix0 = __builtin_amdgcn_sbfe((int)xw, 0, 8);      // v_bfe_i32
      const int in0 = (int)__builtin_amdgcn_ubfe(xw, 8, 8);      // v_bfe_u32
      const int ix1 = __builtin_amdgcn_sbfe((int)xw, 16, 8);
      const int in1 = (int)(xw >> 24);
      int iw0, iw1;
      if (j & 1) { iw0 = __builtin_amdgcn_sbfe((int)ww, 16, 8);
                   iw1 = __builtin_amdgcn_sbfe((int)ww, 24, 8); }
      else       { iw0 = __builtin_amdgcn_sbfe((int)ww, 0, 8);
                   iw1 = __builtin_amdgcn_sbfe((int)ww, 8, 8); }
      bacc += naf_keep(__mul24(ix0, iw0), in0 + s);     // |ix|,|iw| <= 127: exact
      bacc += naf_keep(__mul24(ix1, iw1), in1 + s);
    }
    facc += sxs[tn][b] * sws[to][b] * (float)bacc;  // exact: block_dot = bacc/4096
  }

  if (kh) sred[(kh - 1) * 128 + idx] = facc;
  __syncthreads();
  if (!kh) {
    float r = facc;
#pragma unroll
    for (int p = 0; p < 7; ++p) r += sred[p * 128 + idx];
    r = r * (1.0f / 4096.0f) + bias[o0 + to];
    out[(size_t)(n0 + tn) * ODIM + (o0 + to)] = r;
  }
}

extern "C" void kernel_launch(void* const* d_in, const int* in_sizes, int n_in,
                              void* d_out, int out_size, void* d_ws, size_t ws_size,
                              hipStream_t stream) {
  const float* x    = (const float*)d_in[0];
  const float* wgt  = (const float*)d_in[1];
  const float* bias = (const float*)d_in[2];
  float* out = (float*)d_out;
  char* ws = (char*)d_ws;
  // workspace layout (16B-aligned)
  unsigned short* xp  = (unsigned short*)(ws + 0);       // 262144 B
  unsigned char*  wq  = (unsigned char*)(ws + 262144);   // 524288 B
  float* xs  = (float*)(ws + 786432);
  float* lxs = (float*)(ws + 802816);
  float* wsc = (float*)(ws + 819200);
  float* lws = (float*)(ws + 884736);

  hipLaunchKernelGGL(prep_kernel, dim3(80), dim3(256), 0, stream,
                     x, wgt, xp, wq, xs, lxs, wsc, lws);
  hipLaunchKernelGGL(msd_main_kernel, dim3(16, 32), dim3(1024), 0, stream,
                     xp, wq, xs, lxs, wsc, lws, bias, out);
}